// Round 4
// baseline (52.403 us; speedup 1.0000x reference)
//
#include <hip/hip_runtime.h>

#define NB 8
#define NS 2048
#define ND 128
#define NK 16

typedef float f32x4 __attribute__((ext_vector_type(4)));

// DPP cross-lane move of a double (both 32-bit halves). CTRL compile-time.
template <int CTRL>
__device__ inline double dpp_f64(double v) {
    long long b = __double_as_longlong(v);
    int lo = (int)(unsigned int)b;
    int hi = (int)(b >> 32);
    lo = __builtin_amdgcn_update_dpp(0, lo, CTRL, 0xF, 0xF, true);
    hi = __builtin_amdgcn_update_dpp(0, hi, CTRL, 0xF, 0xF, true);
    return __longlong_as_double(((long long)hi << 32) | (unsigned int)lo);
}

__device__ inline double shfl_xor_f64(double v, int mask) {
    long long b = __double_as_longlong(v);
    int lo = __shfl_xor((int)(unsigned int)b, mask, 64);
    int hi = __shfl_xor((int)(b >> 32), mask, 64);
    return __longlong_as_double(((long long)hi << 32) | (unsigned int)lo);
}

// min over all 64 lanes, result in every lane. xor{1,2,7,15} via DPP (VALU
// pipe), xor{16,32} via shfl (LDS pipe). Span{1,2,7,15,16,32} = 0..63.
__device__ inline double wave_min_f64(double v) {
    v = fmin(v, dpp_f64<0xB1>(v));   // quad_perm [1,0,3,2]  : xor 1
    v = fmin(v, dpp_f64<0x4E>(v));   // quad_perm [2,3,0,1]  : xor 2
    v = fmin(v, dpp_f64<0x141>(v));  // row_half_mirror      : xor 7
    v = fmin(v, dpp_f64<0x140>(v));  // row_mirror           : xor 15
    v = fmin(v, shfl_xor_f64(v, 16));
    v = fmin(v, shfl_xor_f64(v, 32));
    return v;
}

// Batcher odd-even mergesort of N keys (static indices, fully unrolled).
template <int N>
__device__ inline void batcher_sort(double* k) {
#pragma unroll
    for (int p = 1; p < N; p <<= 1) {
#pragma unroll
        for (int kk = p; kk >= 1; kk >>= 1) {
#pragma unroll
            for (int j = kk & (p - 1); j + kk < N; j += 2 * kk) {
#pragma unroll
                for (int ii = 0; ii < kk; ++ii) {
                    const int a = ii + j;
                    const int c = ii + j + kk;
                    if (c < N && (a / (2 * p)) == (c / (2 * p))) {
                        const double ka = k[a];
                        const double kc = k[c];
                        k[a] = fmin(ka, kc);
                        k[c] = fmax(ka, kc);
                    }
                }
            }
        }
    }
}

__global__ __launch_bounds__(256) void knn_kernel(
    const float* __restrict__ pts,   // [B,S,3]
    const int*   __restrict__ fidx,  // [B,S,1]
    const float* __restrict__ attr,  // [B,S,D]
    float*       __restrict__ out)   // out0 [B,S,K] | out1 [B,S,K] | out2 [B,S,K,D]
{
    // Per-lane list slots 0..11 = sorted elements 4..15; 12..15 = PAD.
    // 17-slot stride breaks the 128B-stride bank pathologies.
    __shared__ double sorted[4][64][17];

    const int wv   = threadIdx.x >> 6;
    const int lane = threadIdx.x & 63;
    const int row  = blockIdx.x * 4 + wv;    // [0, B*S)
    const int b = row >> 11;
    const int i = row & 2047;

    const float* pb = pts + (size_t)b * NS * 3;
    const float qx = pb[i * 3 + 0];
    const float qy = pb[i * 3 + 1];
    const float qz = pb[i * 3 + 2];

    // Monotone f64 key: bits = 0x3FF<<52 | dist_bits<<20 | j<<9.
    // Positive normal doubles in [1,2): f64 order == (dist_bits, j) lex order.
    double keys[32];
#pragma unroll
    for (int t = 0; t < 32; ++t) {
        const int j = t * 64 + lane;
        const float x = pb[j * 3 + 0];
        const float y = pb[j * 3 + 1];
        const float z = pb[j * 3 + 2];
        const float dx = __fsub_rn(qx, x);
        const float dy = __fsub_rn(qy, y);
        const float dz = __fsub_rn(qz, z);
        // exact left-to-right, no FMA contraction (matches reference arithmetic)
        float d = __fmul_rn(dx, dx);
        d = __fadd_rn(d, __fmul_rn(dy, dy));
        d = __fadd_rn(d, __fmul_rn(dz, dz));
        const unsigned int db = __float_as_uint(d);
        const unsigned int hi = 0x3FF00000u | (db >> 12);
        const unsigned int lo = (db << 20) | ((unsigned int)j << 9);
        keys[t] = __longlong_as_double(((long long)hi << 32) | lo);
    }

    // Partial sort: top-16 of 32, sorted ascending.
    batcher_sort<16>(keys);        // keys[0..15] asc
    batcher_sort<16>(keys + 16);   // keys[16..31] asc
    double c[16];
#pragma unroll
    for (int t = 0; t < 16; ++t) c[t] = fmin(keys[t], keys[31 - t]);  // bitonic low half
#pragma unroll
    for (int d = 8; d >= 1; d >>= 1) {                                // bitonic clean
#pragma unroll
        for (int t = 0; t < 16; ++t) {
            if ((t & d) == 0 && (t | d) < 16) {
                const double ka = c[t];
                const double kc = c[t | d];
                c[t] = fmin(ka, kc);
                c[t | d] = fmax(ka, kc);
            }
        }
    }

    // Spill elements 4..15 (+4 PADs); elements 0..3 live in the reg window.
    const double PAD = __longlong_as_double(0x7FE0000000000000LL);
    double* myLds = &sorted[wv][lane][0];
#pragma unroll
    for (int t = 0; t < 12; ++t) myLds[t] = c[t + 4];
#pragma unroll
    for (int t = 12; t < 16; ++t) myLds[t] = PAD;

    // 16-round tournament; pops are register-only (4-deep sliding window,
    // background LDS refill issued at round start, consumed only on pop).
    double w0 = c[0], w1 = c[1], w2 = c[2], w3 = c[3];
    int hp = 0;
    double myKey = 0.0;                // lane k holds round-k winner
#pragma unroll
    for (int k = 0; k < NK; ++k) {
        const double rd = myLds[hp];   // element hp+4 (PAD beyond 15)
        const double mn = wave_min_f64(w0);
        if (lane == k) myKey = mn;
        const bool pop = (w0 == mn);   // keys globally unique -> single winner
        w0 = pop ? w1 : w0;
        w1 = pop ? w2 : w1;
        w2 = pop ? w3 : w2;
        w3 = pop ? rd : w3;
        hp += pop ? 1 : 0;
    }

    float* out0 = out;                                   // [B,S,K]
    float* out1 = out + (size_t)NB * NS * NK;            // [B,S,K]
    float* out2 = out + (size_t)2 * NB * NS * NK;        // [B,S,K,D]
    const size_t rowBase = (size_t)row * NK;

    const long long kb = __double_as_longlong(myKey);
    const int myJ = (int)((kb >> 9) & 0x7FF);

    if (lane < NK) {
        const unsigned int db = (unsigned int)(kb >> 20);
        out0[rowBase + lane] = __uint_as_float(db);
        const int ii = fidx[(size_t)b * NS + i];
        const int jj = fidx[(size_t)b * NS + myJ];
        out1[rowBase + lane] = fabsf((float)(ii - jj));
    }

    // Gather attribute rows: 2 neighbor rows per pass (512B each), skewed
    // load->store pipeline, non-temporal stores for the 128MB stream.
    const int half = lane >> 5;      // 0 or 1
    const int comp = lane & 31;      // float4 slot within the 128-float row
    const float* ab = attr + (size_t)b * NS * ND;
    float* o2row = out2 + rowBase * ND;

    unsigned int jj8[8];
#pragma unroll
    for (int p = 0; p < 8; ++p)
        jj8[p] = (unsigned int)__shfl(myJ, 2 * p + half, 64);

    f32x4 cur = *(const f32x4*)(ab + (size_t)jj8[0] * ND + comp * 4);
#pragma unroll
    for (int p = 0; p < 8; ++p) {
        f32x4 nxt = cur;
        if (p < 7) nxt = *(const f32x4*)(ab + (size_t)jj8[p + 1] * ND + comp * 4);
        __builtin_nontemporal_store(
            cur, (f32x4*)(o2row + (size_t)(2 * p + half) * ND + comp * 4));
        cur = nxt;
    }
}

extern "C" void kernel_launch(void* const* d_in, const int* in_sizes, int n_in,
                              void* d_out, int out_size, void* d_ws, size_t ws_size,
                              hipStream_t stream) {
    const float* pts  = (const float*)d_in[0];
    const int*   fidx = (const int*)d_in[1];
    const float* attr = (const float*)d_in[2];
    float* out = (float*)d_out;

    const int rows = NB * NS;                 // 16384
    const int blocks = rows / 4;              // 4096 blocks, 4 waves each
    knn_kernel<<<blocks, 256, 0, stream>>>(pts, fidx, attr, out);
}